// Round 5
// baseline (295.400 us; speedup 1.0000x reference)
//
#include <hip/hip_runtime.h>

#define SDIM 16384
#define RANK 64
#define NMID 6
#define NCHUNK 8
#define CHUNK_LEN (SDIM / NCHUNK)           // 2048
#define VMID_BLOCKS (NMID * RANK * NCHUNK)  // 3072
#define VLAST_BLOCKS RANK                   // 64

// clang-native vector type: accepted by __builtin_nontemporal_load
typedef float float4n __attribute__((ext_vector_type(4)));

// ---------------------------------------------------------------------------
// Kernel A: V_last (blocks 0..63) + partial V_mid (blocks 64..3135).
// vmid block: one (k,a) pair, one s-chunk.  z-chunk staged in LDS so the
// global stream is pure float4 nontemporal reads of tt_mid.
// Deterministic (fixed-order LDS reduce, no atomics).
// ---------------------------------------------------------------------------
__global__ __launch_bounds__(256) void k_contract(
    const float* __restrict__ z, const float* __restrict__ tt_mid,
    const float* __restrict__ tt_last, float* __restrict__ part,
    float* __restrict__ vlast) {
  if (blockIdx.x >= VLAST_BLOCKS) {
    const int idx = blockIdx.x - VLAST_BLOCKS;
    const int c  = idx & (NCHUNK - 1);
    const int ka = idx / NCHUNK;                    // k*64 + a, 0..383
    const float* __restrict__ src =
        tt_mid + ((size_t)ka * SDIM + (size_t)c * CHUNK_LEN) * RANK;
    const float* __restrict__ zz = z + (size_t)c * CHUNK_LEN;

    // Stage z-chunk (8 KB) into LDS: removes the per-iter global z load.
    __shared__ float zs[CHUNK_LEN];
#pragma unroll
    for (int i = threadIdx.x; i < CHUNK_LEN / 4; i += 256)
      reinterpret_cast<float4n*>(zs)[i] =
          reinterpret_cast<const float4n*>(zz)[i];
    __syncthreads();

    const int b8  = threadIdx.x & 7;                // which 32B of 256B row
    const int row = threadIdx.x >> 3;               // 0..31

    float4n acc0 = {0.f, 0.f, 0.f, 0.f};
    float4n acc1 = {0.f, 0.f, 0.f, 0.f};
#pragma unroll 4
    for (int s = row; s < CHUNK_LEN; s += 32) {
      const float w = zs[s];
      const float4n* p =
          reinterpret_cast<const float4n*>(src + (size_t)s * RANK + b8 * 8);
      const float4n v0 = __builtin_nontemporal_load(p);
      const float4n v1 = __builtin_nontemporal_load(p + 1);
      acc0 += w * v0;
      acc1 += w * v1;
    }

    __shared__ float4n lds[512];
    lds[threadIdx.x * 2]     = acc0;
    lds[threadIdx.x * 2 + 1] = acc1;
    __syncthreads();
    if (threadIdx.x < 16) {
      float4n sum = {0.f, 0.f, 0.f, 0.f};
      for (int r = 0; r < 32; ++r) sum += lds[r * 16 + threadIdx.x];
      *reinterpret_cast<float4n*>(
          part + ((size_t)ka * NCHUNK + c) * RANK + threadIdx.x * 4) = sum;
    }
  } else {
    // V_last[a] = sum_s z[s] * tt_last[a, s, 0]
    const int a = blockIdx.x;
    const float* __restrict__ src = tt_last + (size_t)a * SDIM;
    float acc = 0.f;
    for (int i = threadIdx.x; i < SDIM / 4; i += 256) {
      const float4n v = *reinterpret_cast<const float4n*>(src + i * 4);
      const float4n w = *reinterpret_cast<const float4n*>(z + i * 4);
      acc += v.x * w.x + v.y * w.y + v.z * w.z + v.w * w.w;
    }
    __shared__ float red[256];
    red[threadIdx.x] = acc;
    __syncthreads();
    for (int off = 128; off > 0; off >>= 1) {
      if (threadIdx.x < off) red[threadIdx.x] += red[threadIdx.x + off];
      __syncthreads();
    }
    if (threadIdx.x == 0) vlast[a] = red[0];
  }
}

// ---------------------------------------------------------------------------
// Kernel B: parallel fold of chunk partials into V.  grid = 384 blocks.
// ---------------------------------------------------------------------------
__global__ __launch_bounds__(64) void k_fold(
    const float* __restrict__ part, float* __restrict__ V) {
  const int ka = blockIdx.x;
  const int b  = threadIdx.x;
  float s = 0.f;
#pragma unroll
  for (int c = 0; c < NCHUNK; ++c)
    s += part[((size_t)ka * NCHUNK + c) * RANK + b];
  V[(size_t)ka * RANK + b] = s;
}

// ---------------------------------------------------------------------------
// Kernel C: fused chain + output.  grid = 256 blocks x 64 rows.
// Each block redundantly computes u = V_0 @ ... @ V_5 @ V_last (L2-resident,
// identical fixed order -> deterministic), then out[r] = <tt_first[r,:], u>
// for its 64 rows (4 groups of 16).
// ---------------------------------------------------------------------------
__global__ __launch_bounds__(256) void k_chain_out(
    const float* __restrict__ V, const float* __restrict__ vlast,
    const float* __restrict__ tt_first, float* __restrict__ out) {
  __shared__ float su[RANK];
  __shared__ float snew[RANK];
  __shared__ float red[256];
  if (threadIdx.x < RANK) su[threadIdx.x] = vlast[threadIdx.x];
  __syncthreads();

  const int a = threadIdx.x >> 2;   // row 0..63
  const int t = threadIdx.x & 3;    // 4 threads per row
  for (int k = NMID - 1; k >= 0; --k) {
    const float* __restrict__ Vk =
        V + (size_t)k * RANK * RANK + (size_t)a * RANK + t * 16;
    float s = 0.f;
#pragma unroll
    for (int b = 0; b < 16; ++b) s += Vk[b] * su[t * 16 + b];
    red[threadIdx.x] = s;
    __syncthreads();
    if (t == 0)
      snew[a] = red[a * 4] + red[a * 4 + 1] + red[a * 4 + 2] + red[a * 4 + 3];
    __syncthreads();
    if (threadIdx.x < RANK) su[threadIdx.x] = snew[threadIdx.x];
    __syncthreads();
  }

  // out[r] = dot(tt_first[r,:], u)   -- 16 lanes per row, u in LDS
  const int j = threadIdx.x & 15;
  const float4n w = *reinterpret_cast<const float4n*>(su + j * 4);
#pragma unroll
  for (int g = 0; g < 4; ++g) {
    const int r = blockIdx.x * 64 + g * 16 + (threadIdx.x >> 4);
    const float4n v =
        *reinterpret_cast<const float4n*>(tt_first + (size_t)r * RANK + j * 4);
    float s = v.x * w.x + v.y * w.y + v.z * w.z + v.w * w.w;
    s += __shfl_xor(s, 1, 16);
    s += __shfl_xor(s, 2, 16);
    s += __shfl_xor(s, 4, 16);
    s += __shfl_xor(s, 8, 16);
    if (j == 0) out[r] = s;
  }
}

// ---------------------------------------------------------------------------
extern "C" void kernel_launch(void* const* d_in, const int* in_sizes, int n_in,
                              void* d_out, int out_size, void* d_ws,
                              size_t ws_size, hipStream_t stream) {
  const float* z        = (const float*)d_in[0];
  const float* tt_first = (const float*)d_in[1];
  const float* tt_mid   = (const float*)d_in[2];
  const float* tt_last  = (const float*)d_in[3];
  float* out = (float*)d_out;
  float* ws  = (float*)d_ws;

  float* part  = ws;                                         // 196608 floats
  float* V     = part + (size_t)NMID * RANK * NCHUNK * RANK; // 24576 floats
  float* vlast = V + (size_t)NMID * RANK * RANK;             // 64

  k_contract<<<VLAST_BLOCKS + VMID_BLOCKS, 256, 0, stream>>>(
      z, tt_mid, tt_last, part, vlast);
  k_fold<<<NMID * RANK, 64, 0, stream>>>(part, V);
  k_chain_out<<<SDIM / 64, 256, 0, stream>>>(V, vlast, tt_first, out);
}

// Round 6
// 285.628 us; speedup vs baseline: 1.0342x; 1.0342x over previous
//
#include <hip/hip_runtime.h>

#define SDIM 16384
#define RANK 64
#define NMID 6
#define NCHUNK 16
#define CHUNK_LEN (SDIM / NCHUNK)            // 1024
#define NUNITS (NMID * RANK * NCHUNK)        // 6144
#define VMID_GRID 2048                       // co-resident blocks; 3 units each
#define UNITS_PER_BLOCK (NUNITS / VMID_GRID) // 3
#define VLAST_BLOCKS RANK                    // 64

// ---------------------------------------------------------------------------
// Kernel A: V_last (blocks 0..63) + partial V_mid (blocks 64..2111).
// Each vmid block processes 3 units (unit = one (ka, chunk) pair) so the
// grid is exactly 8 blocks/CU co-resident and all blocks finish together.
// Deterministic (fixed-order LDS reduce, no atomics).
// ---------------------------------------------------------------------------
__global__ __launch_bounds__(256) void k_contract(
    const float* __restrict__ z, const float* __restrict__ tt_mid,
    const float* __restrict__ tt_last, float* __restrict__ part,
    float* __restrict__ vlast) {
  if (blockIdx.x >= VLAST_BLOCKS) {
    const int bid = blockIdx.x - VLAST_BLOCKS;   // 0..2047
    const int b8  = threadIdx.x & 7;             // which 32B of 256B row
    const int row = threadIdx.x >> 3;            // 0..31

    __shared__ float4 lds[512];

#pragma unroll
    for (int j = 0; j < UNITS_PER_BLOCK; ++j) {
      const int u  = bid + j * VMID_GRID;        // unit id 0..6143
      const int c  = u & (NCHUNK - 1);
      const int ka = u >> 4;                     // u / NCHUNK
      const float* __restrict__ src =
          tt_mid + ((size_t)ka * SDIM + (size_t)c * CHUNK_LEN) * RANK;
      const float* __restrict__ zz = z + (size_t)c * CHUNK_LEN;

      float4 acc0 = {0.f, 0.f, 0.f, 0.f};
      float4 acc1 = {0.f, 0.f, 0.f, 0.f};
#pragma unroll 4
      for (int s = row; s < CHUNK_LEN; s += 32) {
        const float w = zz[s];
        const float4* p =
            reinterpret_cast<const float4*>(src + (size_t)s * RANK + b8 * 8);
        const float4 v0 = p[0];
        const float4 v1 = p[1];
        acc0.x += w * v0.x; acc0.y += w * v0.y;
        acc0.z += w * v0.z; acc0.w += w * v0.w;
        acc1.x += w * v1.x; acc1.y += w * v1.y;
        acc1.z += w * v1.z; acc1.w += w * v1.w;
      }

      __syncthreads();   // previous unit's LDS reads complete before overwrite
      lds[threadIdx.x * 2]     = acc0;
      lds[threadIdx.x * 2 + 1] = acc1;
      __syncthreads();
      if (threadIdx.x < 16) {
        float4 sum = {0.f, 0.f, 0.f, 0.f};
        for (int r = 0; r < 32; ++r) {
          const float4 t = lds[r * 16 + threadIdx.x];
          sum.x += t.x; sum.y += t.y; sum.z += t.z; sum.w += t.w;
        }
        *reinterpret_cast<float4*>(
            part + ((size_t)ka * NCHUNK + c) * RANK + threadIdx.x * 4) = sum;
      }
    }
  } else {
    // V_last[a] = sum_s z[s] * tt_last[a, s, 0]
    const int a = blockIdx.x;
    const float* __restrict__ src = tt_last + (size_t)a * SDIM;
    float acc = 0.f;
    for (int i = threadIdx.x; i < SDIM / 4; i += 256) {
      const float4 v = *reinterpret_cast<const float4*>(src + i * 4);
      const float4 w = *reinterpret_cast<const float4*>(z + i * 4);
      acc += v.x * w.x + v.y * w.y + v.z * w.z + v.w * w.w;
    }
    __shared__ float red[256];
    red[threadIdx.x] = acc;
    __syncthreads();
    for (int off = 128; off > 0; off >>= 1) {
      if (threadIdx.x < off) red[threadIdx.x] += red[threadIdx.x + off];
      __syncthreads();
    }
    if (threadIdx.x == 0) vlast[a] = red[0];
  }
}

// ---------------------------------------------------------------------------
// Kernel B: fold chunk partials into V.  24576 outputs = 96 blocks x 256 thr.
// V[ka*64 + b] = sum_c part[(ka*NCHUNK + c)*64 + b]
// ---------------------------------------------------------------------------
__global__ __launch_bounds__(256) void k_fold(
    const float* __restrict__ part, float* __restrict__ V) {
  const int e  = blockIdx.x * 256 + threadIdx.x;   // 0..24575
  const int ka = e >> 6;
  const int b  = e & 63;
  float s = 0.f;
#pragma unroll
  for (int c = 0; c < NCHUNK; ++c)
    s += part[((size_t)ka * NCHUNK + c) * RANK + b];
  V[e] = s;
}

// ---------------------------------------------------------------------------
// Kernel C: fused chain + output.  grid = 1024 blocks x 16 rows.
// Each block redundantly computes u = V_0 @ ... @ V_5 @ V_last (L2-resident,
// identical fixed order -> deterministic), then out[r] = <tt_first[r,:], u>.
// ---------------------------------------------------------------------------
__global__ __launch_bounds__(256) void k_chain_out(
    const float* __restrict__ V, const float* __restrict__ vlast,
    const float* __restrict__ tt_first, float* __restrict__ out) {
  __shared__ float su[RANK];
  __shared__ float snew[RANK];
  __shared__ float red[256];
  if (threadIdx.x < RANK) su[threadIdx.x] = vlast[threadIdx.x];
  __syncthreads();

  const int a = threadIdx.x >> 2;   // row 0..63
  const int t = threadIdx.x & 3;    // 4 threads per row
  for (int k = NMID - 1; k >= 0; --k) {
    const float* __restrict__ Vk =
        V + (size_t)k * RANK * RANK + (size_t)a * RANK + t * 16;
    float s = 0.f;
#pragma unroll
    for (int b = 0; b < 16; ++b) s += Vk[b] * su[t * 16 + b];
    red[threadIdx.x] = s;
    __syncthreads();
    if (t == 0)
      snew[a] = red[a * 4] + red[a * 4 + 1] + red[a * 4 + 2] + red[a * 4 + 3];
    __syncthreads();
    if (threadIdx.x < RANK) su[threadIdx.x] = snew[threadIdx.x];
    __syncthreads();
  }

  // out[r] = dot(tt_first[r,:], u)   -- 16 lanes per row, u in LDS
  const int r = blockIdx.x * 16 + (threadIdx.x >> 4);
  const int j = threadIdx.x & 15;
  const float4 v =
      *reinterpret_cast<const float4*>(tt_first + (size_t)r * RANK + j * 4);
  const float4 w = *reinterpret_cast<const float4*>(su + j * 4);
  float s = v.x * w.x + v.y * w.y + v.z * w.z + v.w * w.w;
  s += __shfl_xor(s, 1, 16);
  s += __shfl_xor(s, 2, 16);
  s += __shfl_xor(s, 4, 16);
  s += __shfl_xor(s, 8, 16);
  if (j == 0) out[r] = s;
}

// ---------------------------------------------------------------------------
extern "C" void kernel_launch(void* const* d_in, const int* in_sizes, int n_in,
                              void* d_out, int out_size, void* d_ws,
                              size_t ws_size, hipStream_t stream) {
  const float* z        = (const float*)d_in[0];
  const float* tt_first = (const float*)d_in[1];
  const float* tt_mid   = (const float*)d_in[2];
  const float* tt_last  = (const float*)d_in[3];
  float* out = (float*)d_out;
  float* ws  = (float*)d_ws;

  float* part  = ws;                                         // 393216 floats
  float* V     = part + (size_t)NMID * RANK * NCHUNK * RANK; // 24576 floats
  float* vlast = V + (size_t)NMID * RANK * RANK;             // 64

  k_contract<<<VLAST_BLOCKS + VMID_GRID, 256, 0, stream>>>(
      z, tt_mid, tt_last, part, vlast);
  k_fold<<<NMID * RANK * RANK / 256, 256, 0, stream>>>(part, V);
  k_chain_out<<<SDIM / 16, 256, 0, stream>>>(V, vlast, tt_first, out);
}

// Round 7
// 275.503 us; speedup vs baseline: 1.0722x; 1.0368x over previous
//
#include <hip/hip_runtime.h>

#define SDIM 16384
#define RANK 64
#define NMID 6
#define NCHUNK 8
#define CHUNK_LEN (SDIM / NCHUNK)   // 2048
#define VMID_BLOCKS (NMID * RANK * NCHUNK)  // 3072

// ---------------------------------------------------------------------------
// Kernel A: partial V_mid (blocks 0..3071) + V_last (blocks 3072..3135).
// vmid block: one (k,a) pair, one s-chunk.  8 x 32B col groups x 32 s-rows.
// Deterministic (fixed-order LDS reduce, no atomics).
// NOTE (R4/R5/R6 lessons): z staged in LDS, nontemporal loads, and the
// balanced multi-unit grid each REGRESSED — keep this structure simple.
// ---------------------------------------------------------------------------
__global__ __launch_bounds__(256) void k_contract(
    const float* __restrict__ z, const float* __restrict__ tt_mid,
    const float* __restrict__ tt_last, float* __restrict__ part,
    float* __restrict__ vlast) {
  if (blockIdx.x < VMID_BLOCKS) {
    const int idx = blockIdx.x;
    const int c  = idx & (NCHUNK - 1);
    const int ka = idx / NCHUNK;                    // k*64 + a, 0..383
    const float* __restrict__ src =
        tt_mid + ((size_t)ka * SDIM + (size_t)c * CHUNK_LEN) * RANK;
    const float* __restrict__ zz = z + (size_t)c * CHUNK_LEN;

    const int b8  = threadIdx.x & 7;                // which 32B of 256B row
    const int row = threadIdx.x >> 3;               // 0..31

    float4 acc0 = {0.f, 0.f, 0.f, 0.f};
    float4 acc1 = {0.f, 0.f, 0.f, 0.f};
#pragma unroll 4
    for (int s = row; s < CHUNK_LEN; s += 32) {
      const float w = zz[s];
      const float4* p =
          reinterpret_cast<const float4*>(src + (size_t)s * RANK + b8 * 8);
      const float4 v0 = p[0];
      const float4 v1 = p[1];
      acc0.x += w * v0.x; acc0.y += w * v0.y;
      acc0.z += w * v0.z; acc0.w += w * v0.w;
      acc1.x += w * v1.x; acc1.y += w * v1.y;
      acc1.z += w * v1.z; acc1.w += w * v1.w;
    }

    __shared__ float4 lds[512];
    lds[threadIdx.x * 2]     = acc0;
    lds[threadIdx.x * 2 + 1] = acc1;
    __syncthreads();
    if (threadIdx.x < 16) {
      float4 sum = {0.f, 0.f, 0.f, 0.f};
      for (int r = 0; r < 32; ++r) {
        const float4 t = lds[r * 16 + threadIdx.x];
        sum.x += t.x; sum.y += t.y; sum.z += t.z; sum.w += t.w;
      }
      *reinterpret_cast<float4*>(
          part + ((size_t)ka * NCHUNK + c) * RANK + threadIdx.x * 4) = sum;
    }
  } else {
    // V_last[a] = sum_s z[s] * tt_last[a, s, 0]
    const int a = blockIdx.x - VMID_BLOCKS;
    const float* __restrict__ src = tt_last + (size_t)a * SDIM;
    float acc = 0.f;
    for (int i = threadIdx.x; i < SDIM / 4; i += 256) {
      const float4 v = *reinterpret_cast<const float4*>(src + i * 4);
      const float4 w = *reinterpret_cast<const float4*>(z + i * 4);
      acc += v.x * w.x + v.y * w.y + v.z * w.z + v.w * w.w;
    }
    __shared__ float red[256];
    red[threadIdx.x] = acc;
    __syncthreads();
    for (int off = 128; off > 0; off >>= 1) {
      if (threadIdx.x < off) red[threadIdx.x] += red[threadIdx.x + off];
      __syncthreads();
    }
    if (threadIdx.x == 0) vlast[a] = red[0];
  }
}

// ---------------------------------------------------------------------------
// Kernel B: parallel fold of chunk partials into V.  grid = 384 blocks.
// ---------------------------------------------------------------------------
__global__ __launch_bounds__(64) void k_fold(
    const float* __restrict__ part, float* __restrict__ V) {
  const int ka = blockIdx.x;
  const int b  = threadIdx.x;
  float s = 0.f;
#pragma unroll
  for (int c = 0; c < NCHUNK; ++c)
    s += part[((size_t)ka * NCHUNK + c) * RANK + b];
  V[(size_t)ka * RANK + b] = s;
}

// ---------------------------------------------------------------------------
// Kernel C: fused chain + output.  grid = 1024 blocks, 256 threads.
// Each block redundantly computes u = V_0 @ ... @ V_5 @ V_last (L2-resident,
// identical fixed order in every block -> deterministic & consistent), then
// writes out[r] = dot(tt_first[r,:], u) for its 16 rows.
// ---------------------------------------------------------------------------
__global__ __launch_bounds__(256) void k_chain_out(
    const float* __restrict__ V, const float* __restrict__ vlast,
    const float* __restrict__ tt_first, float* __restrict__ out) {
  __shared__ float su[RANK];
  __shared__ float snew[RANK];
  __shared__ float red[256];
  if (threadIdx.x < RANK) su[threadIdx.x] = vlast[threadIdx.x];
  __syncthreads();

  const int a = threadIdx.x >> 2;   // row 0..63
  const int t = threadIdx.x & 3;    // 4 threads per row
  for (int k = NMID - 1; k >= 0; --k) {
    const float* __restrict__ Vk =
        V + (size_t)k * RANK * RANK + (size_t)a * RANK + t * 16;
    float s = 0.f;
#pragma unroll
    for (int b = 0; b < 16; ++b) s += Vk[b] * su[t * 16 + b];
    red[threadIdx.x] = s;
    __syncthreads();
    if (t == 0)
      snew[a] = red[a * 4] + red[a * 4 + 1] + red[a * 4 + 2] + red[a * 4 + 3];
    __syncthreads();
    if (threadIdx.x < RANK) su[threadIdx.x] = snew[threadIdx.x];
    __syncthreads();
  }

  // out[r] = dot(tt_first[r,:], u)   -- 16 lanes per row, u in LDS
  const int r = blockIdx.x * 16 + (threadIdx.x >> 4);
  const int j = threadIdx.x & 15;
  const float4 v =
      *reinterpret_cast<const float4*>(tt_first + (size_t)r * RANK + j * 4);
  const float4 w = *reinterpret_cast<const float4*>(su + j * 4);
  float s = v.x * w.x + v.y * w.y + v.z * w.z + v.w * w.w;
  s += __shfl_xor(s, 1, 16);
  s += __shfl_xor(s, 2, 16);
  s += __shfl_xor(s, 4, 16);
  s += __shfl_xor(s, 8, 16);
  if (j == 0) out[r] = s;
}

// ---------------------------------------------------------------------------
extern "C" void kernel_launch(void* const* d_in, const int* in_sizes, int n_in,
                              void* d_out, int out_size, void* d_ws,
                              size_t ws_size, hipStream_t stream) {
  const float* z        = (const float*)d_in[0];
  const float* tt_first = (const float*)d_in[1];
  const float* tt_mid   = (const float*)d_in[2];
  const float* tt_last  = (const float*)d_in[3];
  float* out = (float*)d_out;
  float* ws  = (float*)d_ws;

  float* part  = ws;                                         // 196608 floats
  float* V     = part + (size_t)NMID * RANK * NCHUNK * RANK; // 24576 floats
  float* vlast = V + (size_t)NMID * RANK * RANK;             // 64

  k_contract<<<VMID_BLOCKS + RANK, 256, 0, stream>>>(z, tt_mid, tt_last, part, vlast);
  k_fold<<<NMID * RANK, 64, 0, stream>>>(part, V);
  k_chain_out<<<SDIM / 16, 256, 0, stream>>>(V, vlast, tt_first, out);
}